// Round 21
// baseline (372.769 us; speedup 1.0000x reference)
//
#include <hip/hip_runtime.h>
#include <math.h>

typedef _Float16 f16x8 __attribute__((ext_vector_type(8)));
typedef float f32x4 __attribute__((ext_vector_type(4)));
typedef float f32x16 __attribute__((ext_vector_type(16)));
typedef unsigned short us8 __attribute__((ext_vector_type(8)));
typedef unsigned short us4 __attribute__((ext_vector_type(4)));

#define PI_F 3.14159265358979323846f

__device__ __forceinline__ unsigned short f2h(float f){
  _Float16 hi = (_Float16)f;
  return __builtin_bit_cast(unsigned short, hi);
}

__device__ __forceinline__ float fast_gelu(float v){
  float u2 = v * v;
  float z  = v * fmaf(u2, 0.03567740814f, 0.7978845608f);
  float e  = __builtin_amdgcn_exp2f(z * 2.885390082f);   // 2*log2(e)
  float r  = __builtin_amdgcn_rcpf(e + 1.0f);
  return v - v * r;
}

__device__ __forceinline__ float fast_tanh(float v){
  float e = __builtin_amdgcn_exp2f(v * 2.885390082f);
  float r = __builtin_amdgcn_rcpf(e + 1.0f);
  return 1.0f - 2.0f * r;
}

// LDS tile addressing in ushort units, XOR swizzle for bank balance
#define ACOL(rr,cc) (((rr) << 8) + ((cc) ^ ((((rr) & 15)) << 3)))

#define LDW(ptr) __builtin_bit_cast(f16x8, *reinterpret_cast<const us8*>(ptr))

// ---------------- pyramid (jax.image.resize bilinear, antialias=True) -------
__global__ void pyr_kernel(const float* __restrict__ fg, float* __restrict__ out,
                           int Ho, int Wo, float inv_scale){
  int idx = blockIdx.x * blockDim.x + threadIdx.x;
  int total = 8 * Ho * Wo * 64;
  if (idx >= total) return;
  int c  = idx & 63;
  int xy = idx >> 6;
  int x  = xy % Wo;
  int y  = (xy / Wo) % Ho;
  int b  = xy / (Wo * Ho);
  float cyc = inv_scale * (y + 0.5f) - 0.5f;
  float cxc = inv_scale * (x + 0.5f) - 0.5f;
  int iy0 = (int)ceilf(cyc - inv_scale); if (iy0 < 0) iy0 = 0;
  int iy1 = (int)floorf(cyc + inv_scale); if (iy1 > 63) iy1 = 63;
  int ix0 = (int)ceilf(cxc - inv_scale); if (ix0 < 0) ix0 = 0;
  int ix1 = (int)floorf(cxc + inv_scale); if (ix1 > 63) ix1 = 63;
  float rinv = 1.0f / inv_scale;
  float wxs = 0.0f;
  for (int ix = ix0; ix <= ix1; ++ix){
    float w = 1.0f - fabsf(ix - cxc) * rinv;
    if (w > 0.0f) wxs += w;
  }
  float wys = 0.0f, acc = 0.0f;
  for (int iy = iy0; iy <= iy1; ++iy){
    float wy = 1.0f - fabsf(iy - cyc) * rinv;
    if (wy <= 0.0f) continue;
    wys += wy;
    const float* rowp = fg + (((b * 64) + iy) * 64) * 64 + c;
    for (int ix = ix0; ix <= ix1; ++ix){
      float wx = 1.0f - fabsf(ix - cxc) * rinv;
      if (wx <= 0.0f) continue;
      acc += wy * wx * rowp[ix * 64];
    }
  }
  out[idx] = acc / (wys * wxs);
}

// ------------- posenc table: PE[n][48] f16 (shared across images) -----------
__global__ void pe_kernel(const float* __restrict__ coords,
                          unsigned short* __restrict__ peh){
  int idx = blockIdx.x * 256 + threadIdx.x;   // < 196608
  if (idx >= 16384 * 12) return;
  int n = idx / 12, slot = idx % 12;
  const float cy = coords[2 * n], cx = coords[2 * n + 1];
  if (slot == 0){
    peh[n * 48 + 0] = f2h(cy);
    peh[n * 48 + 1] = f2h(cx);
  } else if (slot <= 10){
    int i = slot - 1;
    float f = PI_F * (float)(1 << i);
    float sy, cyv, sx, cxv;
    sincosf(cy * f, &sy, &cyv);
    sincosf(cx * f, &sx, &cxv);
    peh[n * 48 + 2 + 4 * i] = f2h(sy);
    peh[n * 48 + 3 + 4 * i] = f2h(sx);
    peh[n * 48 + 4 + 4 * i] = f2h(cyv);
    peh[n * 48 + 5 + 4 * i] = f2h(cxv);
  } else {
#pragma unroll
    for (int j = 42; j < 48; ++j) peh[n * 48 + j] = 0;
  }
}

// ------------- weight prep: pre-tiled per-lane 32x32x16 MFMA fragments ------
// WT[l][cfg][ks][lane][e]: col = cfg*32 + (lane&31), k = ks*16 + (lane>>5)*8 + e
// layer0 k-remap: k<42 -> W0 row k; 42..47 pad; 48..239 -> row k-6; 240..255 pad
__global__ void prep_wt(const float* __restrict__ W0, const float* __restrict__ W1,
                        const float* __restrict__ W2, const float* __restrict__ W3,
                        unsigned short* __restrict__ WTh){
  int idx = blockIdx.x * 256 + threadIdx.x;      // < 262144
  int l    = idx >> 16;
  int rem  = idx & 65535;
  int cfg  = rem >> 13;          // 0..7
  int ks   = (rem >> 9) & 15;    // 0..15
  int lane = (rem >> 3) & 63;
  int e    = idx & 7;
  int col  = cfg * 32 + (lane & 31);
  int k    = ks * 16 + (lane >> 5) * 8 + e;
  float v;
  if (l == 0){
    int row; bool valid;
    if (k < 42)                 { row = k;     valid = true; }
    else if (k >= 48 && k < 240){ row = k - 6; valid = true; }
    else                        { row = 0;     valid = false; }
    v = valid ? W0[row * 256 + col] : 0.0f;
  } else {
    const float* W = (l == 1) ? W1 : ((l == 2) ? W2 : W3);
    v = W[k * 256 + col];
  }
  WTh[idx] = f2h(v);
}

// ------------- FiLM params + Wout tiled fragments (16x16 head) --------------
__global__ void prep_misc(const float* __restrict__ cv, const float* __restrict__ Wc,
                          const float* __restrict__ bc, const float* __restrict__ Wout,
                          float* __restrict__ gamma, float* __restrict__ beta,
                          unsigned short* __restrict__ WoT){
  int idx = blockIdx.x * 256 + threadIdx.x;      // < 8192
  if (idx < 4096){
    int b = idx >> 9, j = idx & 511;
    float a = bc[j];
    for (int c = 0; c < 64; ++c) a += cv[b * 64 + c] * Wc[c * 512 + j];
    if (j < 256) gamma[b * 256 + j] = a + 1.0f;
    else         beta[b * 256 + (j - 256)] = a;
  } else {
    int j = idx - 4096;                // WoT[ks][lane][e]
    int ks = j >> 9, lane = (j >> 3) & 63, e = j & 7;
    int col = lane & 15;
    int k = ks * 32 + (lane >> 4) * 8 + e;
    float v = (col < 3) ? Wout[k * 3 + col] : 0.0f;
    WoT[j] = f2h(v);
  }
}

// ------------------------------- main ---------------------------------------
// Wave-private barrier-free MLP: each wave owns rows 32w..32w+31 of T0 and is
// the ONLY reader/writer of those rows after phase 0 — so all 4 layers and
// the head run with ZERO barriers (same-wave LDS ops are program-ordered).
// Activations live in LDS (not registers): footprint = acc[8] in AGPRs +
// Bc[8] ring + temps -> no spill (fixes R19/R20's 195MB scratch). Waves fully
// de-phase: one wave's epilogue VALU overlaps others' MFMA and LDS traffic.
// Epilogue = R16-validated vectorized us4-quad in-place writes. One barrier
// total (post-phase-0, cross-wave row mapping there). 136 KB LDS -> 1 block/CU.
__global__ __launch_bounds__(512, 2)
void dec_main(const float* __restrict__ fg, const float* __restrict__ coords,
              const float* __restrict__ p1, const float* __restrict__ p2,
              const unsigned short* __restrict__ WTh,
              const unsigned short* __restrict__ WoT,
              const unsigned short* __restrict__ peh,
              const float* __restrict__ gamma, const float* __restrict__ beta,
              const float* __restrict__ b0, const float* __restrict__ b1,
              const float* __restrict__ b2, const float* __restrict__ b3,
              const float* __restrict__ bout, float* __restrict__ out){
  __shared__ __align__(16) unsigned short T0[256 * 256];  // 128 KB activation tile
  __shared__ __align__(16) float Pgs[256];                // gamma
  __shared__ __align__(16) float C2s[4][256];             // bs*gm + bt per layer

  const int t  = threadIdx.x;
  const int bi = blockIdx.x >> 6;           // image 0..7
  const int n0 = (blockIdx.x & 63) * 256;   // first coord row of this block

  const int lane = t & 63;
  const int wv   = t >> 6;         // 0..7
  const int l15  = lane & 15;      // head (16x16) lane decode
  const int lg   = lane >> 4;
  const int l31  = lane & 31;      // 32x32 lane decode
  const int lhi  = lane >> 5;      // 0/1
  const int arow = wv * 32 + l31;  // this lane's activation row (0..255)

  // B ring: one fragment per output-col group, refilled after each consume
  f16x8 Bc[8];
#pragma unroll
  for (int c = 0; c < 8; ++c)
    Bc[c] = LDW(WTh + c * 8192 + lane * 8);

  // ---------------- phase 0: params + features into T0 (256 rows) ----------
  if (t < 256){
    const float gm = gamma[bi * 256 + t];
    const float bt = beta[bi * 256 + t];
    Pgs[t] = gm;
    C2s[0][t] = fmaf(b0[t], gm, bt);
    C2s[1][t] = fmaf(b1[t], gm, bt);
    C2s[2][t] = fmaf(b2[t], gm, bt);
    C2s[3][t] = fmaf(b3[t], gm, bt);
  }

#pragma unroll
  for (int pass = 0; pass < 2; ++pass){
    const int r = pass * 128 + (t >> 2), q = t & 3;   // 4 threads/row
    const int n = n0 + r;
    const float cy = coords[2 * n], cx = coords[2 * n + 1];

    if (q == 0){
      if (peh){
        const unsigned short* ph = peh + (size_t)n * 48;
#pragma unroll
        for (int u = 0; u < 6; ++u){
          us8 vh = *reinterpret_cast<const us8*>(ph + u * 8);
          *reinterpret_cast<us8*>(&T0[ACOL(r, u * 8)]) = vh;
        }
      } else {
        float e[48];
        e[0] = cy; e[1] = cx;
#pragma unroll
        for (int i = 0; i < 10; ++i){
          float f = PI_F * (float)(1 << i);
          float sy, cyv, sx, cxv;
          sincosf(cy * f, &sy, &cyv);
          sincosf(cx * f, &sx, &cxv);
          e[2 + 4 * i] = sy;
          e[3 + 4 * i] = sx;
          e[4 + 4 * i] = cyv;
          e[5 + 4 * i] = cxv;
        }
#pragma unroll
        for (int j = 42; j < 48; ++j) e[j] = 0.0f;
#pragma unroll
        for (int u = 0; u < 6; ++u){
          us8 vh;
#pragma unroll
          for (int j = 0; j < 8; ++j) vh[j] = f2h(e[8 * u + j]);
          *reinterpret_cast<us8*>(&T0[ACOL(r, u * 8)]) = vh;
        }
      }
    }
    if (q == 1){   // zero pad cols 240..255
      us8 z = {0,0,0,0,0,0,0,0};
      *reinterpret_cast<us8*>(&T0[ACOL(r, 240)]) = z;
      *reinterpret_cast<us8*>(&T0[ACOL(r, 248)]) = z;
    }

    // bilinear sample 16 channels per thread from each pyramid level
#pragma unroll
    for (int L = 0; L < 3; ++L){
      const int HL = 64 >> L;
      const float* g = (L == 0) ? fg : ((L == 1) ? p1 : p2);
      float yy = (cy + 1.0f) * 0.5f * (HL - 1);
      float xx = (cx + 1.0f) * 0.5f * (HL - 1);
      float y0f = floorf(yy), x0f = floorf(xx);
      float wy = yy - y0f, wx = xx - x0f;
      int y0 = (int)y0f, x0 = (int)x0f;
      y0 = min(max(y0, 0), HL - 1); x0 = min(max(x0, 0), HL - 1);
      int y1 = min(y0 + 1, HL - 1), x1 = min(x0 + 1, HL - 1);
      const int c0 = q * 16;
      const float* g00 = g + (((bi * HL + y0) * HL) + x0) * 64 + c0;
      const float* g01 = g + (((bi * HL + y0) * HL) + x1) * 64 + c0;
      const float* g10 = g + (((bi * HL + y1) * HL) + x0) * 64 + c0;
      const float* g11 = g + (((bi * HL + y1) * HL) + x1) * 64 + c0;
      float w00 = (1 - wy) * (1 - wx), w01 = (1 - wy) * wx;
      float w10 = wy * (1 - wx),       w11 = wy * wx;
      float o[16];
#pragma unroll
      for (int u = 0; u < 4; ++u){
        float4 v0 = *reinterpret_cast<const float4*>(g00 + 4 * u);
        float4 v1 = *reinterpret_cast<const float4*>(g01 + 4 * u);
        float4 v2 = *reinterpret_cast<const float4*>(g10 + 4 * u);
        float4 v3 = *reinterpret_cast<const float4*>(g11 + 4 * u);
        o[4*u+0] = w00*v0.x + w01*v1.x + w10*v2.x + w11*v3.x;
        o[4*u+1] = w00*v0.y + w01*v1.y + w10*v2.y + w11*v3.y;
        o[4*u+2] = w00*v0.z + w01*v1.z + w10*v2.z + w11*v3.z;
        o[4*u+3] = w00*v0.w + w01*v1.w + w10*v2.w + w11*v3.w;
      }
      us8 h0, h1;
#pragma unroll
      for (int j = 0; j < 8; ++j){
        h0[j] = f2h(o[j]);
        h1[j] = f2h(o[8 + j]);
      }
      const int colb = 48 + 64 * L + 16 * q;
      *reinterpret_cast<us8*>(&T0[ACOL(r, colb)])     = h0;
      *reinterpret_cast<us8*>(&T0[ACOL(r, colb + 8)]) = h1;
    }
  }
  __syncthreads();   // the ONLY barrier: phase-0 row mapping is cross-wave

  // ---------------- 4 FiLM-gelu MLP layers, barrier-free -------------------
  f32x16 acc[8];

#pragma unroll
  for (int l = 0; l < 4; ++l){
#pragma unroll
    for (int j = 0; j < 16; ++j){
#pragma unroll
      for (int c = 0; c < 8; ++c) acc[c][j] = 0.0f;
    }

    // K-loop: reads ONLY this wave's rows (arow in [32wv, 32wv+32))
#pragma unroll
    for (int ks = 0; ks < 16; ++ks){
      f16x8 ah = LDW(&T0[ACOL(arow, ks * 16 + lhi * 8)]);
#pragma unroll
      for (int c = 0; c < 8; ++c){
        f16x8 b = Bc[c];
        if (ks < 15)
          Bc[c] = LDW(WTh + l * 65536 + c * 8192 + (ks + 1) * 512 + lane * 8);
        else if (l < 3)
          Bc[c] = LDW(WTh + (l + 1) * 65536 + c * 8192 + lane * 8);
        acc[c] = __builtin_amdgcn_mfma_f32_32x32x16_f16(b, ah, acc[c], 0, 0, 0);
      }
    }

    // epilogue: FiLM+gelu, vectorized us4-quad IN-PLACE writes to own rows.
    // Same-wave LDS ordering: all K-reads of arow precede these writes.
#pragma unroll
    for (int c = 0; c < 8; ++c){
#pragma unroll
      for (int gp = 0; gp < 2; ++gp){
        const int cb2 = c * 32 + 16 * gp + 4 * lhi;
        const float4 gmA = *reinterpret_cast<const float4*>(&Pgs[cb2]);
        const float4 c2A = *reinterpret_cast<const float4*>(&C2s[l][cb2]);
        const float4 gmB = *reinterpret_cast<const float4*>(&Pgs[cb2 + 8]);
        const float4 c2B = *reinterpret_cast<const float4*>(&C2s[l][cb2 + 8]);
        us4 lo4, hi4;
        lo4[0] = f2h(fast_gelu(fmaf(acc[c][8*gp+0], gmA.x, c2A.x)));
        lo4[1] = f2h(fast_gelu(fmaf(acc[c][8*gp+1], gmA.y, c2A.y)));
        lo4[2] = f2h(fast_gelu(fmaf(acc[c][8*gp+2], gmA.z, c2A.z)));
        lo4[3] = f2h(fast_gelu(fmaf(acc[c][8*gp+3], gmA.w, c2A.w)));
        hi4[0] = f2h(fast_gelu(fmaf(acc[c][8*gp+4], gmB.x, c2B.x)));
        hi4[1] = f2h(fast_gelu(fmaf(acc[c][8*gp+5], gmB.y, c2B.y)));
        hi4[2] = f2h(fast_gelu(fmaf(acc[c][8*gp+6], gmB.z, c2B.z)));
        hi4[3] = f2h(fast_gelu(fmaf(acc[c][8*gp+7], gmB.w, c2B.w)));
        *reinterpret_cast<us4*>(&T0[ACOL(arow, cb2)])     = lo4;
        *reinterpret_cast<us4*>(&T0[ACOL(arow, cb2 + 8)]) = hi4;
      }
    }
    // no barrier: next layer reads only this wave's own rows
  }

  // ---------------- head (256 -> 3) + tanh: reads own rows, no barrier -----
#pragma unroll
  for (int s = 0; s < 2; ++s){
    f32x4 ao = (f32x4){0.0f, 0.0f, 0.0f, 0.0f};
#pragma unroll
    for (int ks = 0; ks < 8; ++ks){
      const int kc = ks * 32 + lg * 8;
      f16x8 va = LDW(&T0[ACOL(wv * 32 + s * 16 + l15, kc)]);
      f16x8 vb = LDW(&WoT[(ks * 64 + lane) * 8]);
      ao = __builtin_amdgcn_mfma_f32_16x16x32_f16(va, vb, ao, 0, 0, 0);
    }
    if (l15 < 3){
      const float bo = bout[l15];
#pragma unroll
      for (int rg2 = 0; rg2 < 4; ++rg2){
        const int row = wv * 32 + s * 16 + lg * 4 + rg2;
        out[((size_t)bi * 16384 + n0 + row) * 3 + l15] = fast_tanh(ao[rg2] + bo);
      }
    }
  }
}

// ------------------------------- launch --------------------------------------
extern "C" void kernel_launch(void* const* d_in, const int* in_sizes, int n_in,
                              void* d_out, int out_size, void* d_ws, size_t ws_size,
                              hipStream_t stream){
  (void)in_sizes; (void)n_in; (void)out_size;
  const float* fg     = (const float*)d_in[0];
  const float* cv     = (const float*)d_in[1];
  const float* coords = (const float*)d_in[2];
  const float* Wc     = (const float*)d_in[3];
  const float* bc     = (const float*)d_in[4];
  const float* W0     = (const float*)d_in[5];
  const float* b0     = (const float*)d_in[6];
  const float* W1     = (const float*)d_in[7];
  const float* b1     = (const float*)d_in[8];
  const float* W2     = (const float*)d_in[9];
  const float* b2     = (const float*)d_in[10];
  const float* W3     = (const float*)d_in[11];
  const float* b3     = (const float*)d_in[12];
  const float* Wout   = (const float*)d_in[13];
  const float* bout   = (const float*)d_in[14];

  char* ws = (char*)d_ws;
  float*          p1    = (float*)(ws);                    // 8*32*32*64 f32 = 2 MB
  float*          p2    = (float*)(ws + 2097152);          // 8*16*16*64 f32 = 512 KB
  unsigned short* WTh   = (unsigned short*)(ws + 2621440); // 4*256*256 f16 = 512 KB
  unsigned short* WoT   = (unsigned short*)(ws + 3670016); // 8*64*8 f16
  float*          gam   = (float*)(ws + 3678208);          // 8*256 f32
  float*          bet   = (float*)(ws + 3686400);          // 8*256 f32
  // PE table (optional, 1.5 MB)
  const size_t PEH_OFF = 4194304, PE_END = 5767168;
  bool use_pe = (ws_size >= PE_END);
  unsigned short* PEh = use_pe ? (unsigned short*)(ws + PEH_OFF) : nullptr;
  float* outp = (float*)d_out;

  pyr_kernel<<<dim3(2048), dim3(256), 0, stream>>>(fg, p1, 32, 32, 2.0f);
  pyr_kernel<<<dim3(512),  dim3(256), 0, stream>>>(fg, p2, 16, 16, 4.0f);
  prep_wt  <<<dim3(1024),  dim3(256), 0, stream>>>(W0, W1, W2, W3, WTh);
  prep_misc<<<dim3(32),    dim3(256), 0, stream>>>(cv, Wc, bc, Wout, gam, bet, WoT);
  if (use_pe)
    pe_kernel<<<dim3(768), dim3(256), 0, stream>>>(coords, PEh);
  dec_main <<<dim3(512),   dim3(512), 0, stream>>>(fg, coords, p1, p2, WTh, WoT,
                                                   PEh,
                                                   gam, bet, b0, b1, b2, b3, bout, outp);
}

// Round 22
// 226.231 us; speedup vs baseline: 1.6477x; 1.6477x over previous
//
#include <hip/hip_runtime.h>
#include <math.h>

typedef _Float16 f16x8 __attribute__((ext_vector_type(8)));
typedef float f32x4 __attribute__((ext_vector_type(4)));
typedef float f32x16 __attribute__((ext_vector_type(16)));
typedef unsigned short us8 __attribute__((ext_vector_type(8)));
typedef unsigned short us4 __attribute__((ext_vector_type(4)));

#define PI_F 3.14159265358979323846f

__device__ __forceinline__ unsigned short f2h(float f){
  _Float16 hi = (_Float16)f;
  return __builtin_bit_cast(unsigned short, hi);
}

__device__ __forceinline__ float fast_gelu(float v){
  float u2 = v * v;
  float z  = v * fmaf(u2, 0.03567740814f, 0.7978845608f);
  float e  = __builtin_amdgcn_exp2f(z * 2.885390082f);   // 2*log2(e)
  float r  = __builtin_amdgcn_rcpf(e + 1.0f);
  return v - v * r;
}

__device__ __forceinline__ float fast_tanh(float v){
  float e = __builtin_amdgcn_exp2f(v * 2.885390082f);
  float r = __builtin_amdgcn_rcpf(e + 1.0f);
  return 1.0f - 2.0f * r;
}

// LDS tile addressing in ushort units, XOR swizzle for bank balance
#define ACOL(rr,cc) (((rr) << 8) + ((cc) ^ ((((rr) & 15)) << 3)))

#define LDW(ptr) __builtin_bit_cast(f16x8, *reinterpret_cast<const us8*>(ptr))

// ---------------- pyramid (jax.image.resize bilinear, antialias=True) -------
__global__ void pyr_kernel(const float* __restrict__ fg, float* __restrict__ out,
                           int Ho, int Wo, float inv_scale){
  int idx = blockIdx.x * blockDim.x + threadIdx.x;
  int total = 8 * Ho * Wo * 64;
  if (idx >= total) return;
  int c  = idx & 63;
  int xy = idx >> 6;
  int x  = xy % Wo;
  int y  = (xy / Wo) % Ho;
  int b  = xy / (Wo * Ho);
  float cyc = inv_scale * (y + 0.5f) - 0.5f;
  float cxc = inv_scale * (x + 0.5f) - 0.5f;
  int iy0 = (int)ceilf(cyc - inv_scale); if (iy0 < 0) iy0 = 0;
  int iy1 = (int)floorf(cyc + inv_scale); if (iy1 > 63) iy1 = 63;
  int ix0 = (int)ceilf(cxc - inv_scale); if (ix0 < 0) ix0 = 0;
  int ix1 = (int)floorf(cxc + inv_scale); if (ix1 > 63) ix1 = 63;
  float rinv = 1.0f / inv_scale;
  float wxs = 0.0f;
  for (int ix = ix0; ix <= ix1; ++ix){
    float w = 1.0f - fabsf(ix - cxc) * rinv;
    if (w > 0.0f) wxs += w;
  }
  float wys = 0.0f, acc = 0.0f;
  for (int iy = iy0; iy <= iy1; ++iy){
    float wy = 1.0f - fabsf(iy - cyc) * rinv;
    if (wy <= 0.0f) continue;
    wys += wy;
    const float* rowp = fg + (((b * 64) + iy) * 64) * 64 + c;
    for (int ix = ix0; ix <= ix1; ++ix){
      float wx = 1.0f - fabsf(ix - cxc) * rinv;
      if (wx <= 0.0f) continue;
      acc += wy * wx * rowp[ix * 64];
    }
  }
  out[idx] = acc / (wys * wxs);
}

// ------------- posenc table: PE[n][48] f16 (shared across images) -----------
__global__ void pe_kernel(const float* __restrict__ coords,
                          unsigned short* __restrict__ peh){
  int idx = blockIdx.x * 256 + threadIdx.x;   // < 196608
  if (idx >= 16384 * 12) return;
  int n = idx / 12, slot = idx % 12;
  const float cy = coords[2 * n], cx = coords[2 * n + 1];
  if (slot == 0){
    peh[n * 48 + 0] = f2h(cy);
    peh[n * 48 + 1] = f2h(cx);
  } else if (slot <= 10){
    int i = slot - 1;
    float f = PI_F * (float)(1 << i);
    float sy, cyv, sx, cxv;
    sincosf(cy * f, &sy, &cyv);
    sincosf(cx * f, &sx, &cxv);
    peh[n * 48 + 2 + 4 * i] = f2h(sy);
    peh[n * 48 + 3 + 4 * i] = f2h(sx);
    peh[n * 48 + 4 + 4 * i] = f2h(cyv);
    peh[n * 48 + 5 + 4 * i] = f2h(cxv);
  } else {
#pragma unroll
    for (int j = 42; j < 48; ++j) peh[n * 48 + j] = 0;
  }
}

// ------------- weight prep: pre-tiled per-lane 32x32x16 MFMA fragments ------
// WT[l][cfg][ks][lane][e]: col = cfg*32 + (lane&31), k = ks*16 + (lane>>5)*8 + e
// layer0 k-remap: k<42 -> W0 row k; 42..47 pad; 48..239 -> row k-6; 240..255 pad
__global__ void prep_wt(const float* __restrict__ W0, const float* __restrict__ W1,
                        const float* __restrict__ W2, const float* __restrict__ W3,
                        unsigned short* __restrict__ WTh){
  int idx = blockIdx.x * 256 + threadIdx.x;      // < 262144
  int l    = idx >> 16;
  int rem  = idx & 65535;
  int cfg  = rem >> 13;          // 0..7
  int ks   = (rem >> 9) & 15;    // 0..15
  int lane = (rem >> 3) & 63;
  int e    = idx & 7;
  int col  = cfg * 32 + (lane & 31);
  int k    = ks * 16 + (lane >> 5) * 8 + e;
  float v;
  if (l == 0){
    int row; bool valid;
    if (k < 42)                 { row = k;     valid = true; }
    else if (k >= 48 && k < 240){ row = k - 6; valid = true; }
    else                        { row = 0;     valid = false; }
    v = valid ? W0[row * 256 + col] : 0.0f;
  } else {
    const float* W = (l == 1) ? W1 : ((l == 2) ? W2 : W3);
    v = W[k * 256 + col];
  }
  WTh[idx] = f2h(v);
}

// ------------- FiLM params + Wout tiled fragments (16x16 head) --------------
__global__ void prep_misc(const float* __restrict__ cv, const float* __restrict__ Wc,
                          const float* __restrict__ bc, const float* __restrict__ Wout,
                          float* __restrict__ gamma, float* __restrict__ beta,
                          unsigned short* __restrict__ WoT){
  int idx = blockIdx.x * 256 + threadIdx.x;      // < 8192
  if (idx < 4096){
    int b = idx >> 9, j = idx & 511;
    float a = bc[j];
    for (int c = 0; c < 64; ++c) a += cv[b * 64 + c] * Wc[c * 512 + j];
    if (j < 256) gamma[b * 256 + j] = a + 1.0f;
    else         beta[b * 256 + (j - 256)] = a;
  } else {
    int j = idx - 4096;                // WoT[ks][lane][e]
    int ks = j >> 9, lane = (j >> 3) & 63, e = j & 7;
    int col = lane & 15;
    int k = ks * 32 + (lane >> 4) * 8 + e;
    float v = (col < 3) ? Wout[k * 3 + col] : 0.0f;
    WoT[j] = f2h(v);
  }
}

// ------------------------------- main ---------------------------------------
// Wave-private barrier-free MLP (R21 structure, validated correct) with each
// layer split into TWO sequential column passes of 4 groups each:
//   acc[4] (64 regs) instead of acc[8] (128) — pass A stashes its FiLM+gelu
//   output in 8 f16x8 regs; pass B re-reads the (still intact) row; ALL
//   writes land after every read. Footprint acc 64 + stash 32 + Bc[4] 16 +
//   temps ~30 = ~145 regs << 256 -> kills the R19/R20/R21 spill.
// B ring wraps A->B within a layer and B->next layer's A across layers.
// One barrier total (post-phase-0). 136 KB LDS -> 1 block/CU, 8 waves.
__global__ __launch_bounds__(512, 2)
void dec_main(const float* __restrict__ fg, const float* __restrict__ coords,
              const float* __restrict__ p1, const float* __restrict__ p2,
              const unsigned short* __restrict__ WTh,
              const unsigned short* __restrict__ WoT,
              const unsigned short* __restrict__ peh,
              const float* __restrict__ gamma, const float* __restrict__ beta,
              const float* __restrict__ b0, const float* __restrict__ b1,
              const float* __restrict__ b2, const float* __restrict__ b3,
              const float* __restrict__ bout, float* __restrict__ out){
  __shared__ __align__(16) unsigned short T0[256 * 256];  // 128 KB activation tile
  __shared__ __align__(16) float Pgs[256];                // gamma
  __shared__ __align__(16) float C2s[4][256];             // bs*gm + bt per layer

  const int t  = threadIdx.x;
  const int bi = blockIdx.x >> 6;           // image 0..7
  const int n0 = (blockIdx.x & 63) * 256;   // first coord row of this block

  const int lane = t & 63;
  const int wv   = t >> 6;         // 0..7
  const int l15  = lane & 15;      // head (16x16) lane decode
  const int lg   = lane >> 4;
  const int l31  = lane & 31;      // 32x32 lane decode
  const int lhi  = lane >> 5;      // 0/1
  const int arow = wv * 32 + l31;  // this lane's activation row (0..255)

  // B ring: 4 slots (one per col group in the current pass); init = L0/passA/ks0
  f16x8 Bc[4];
#pragma unroll
  for (int c = 0; c < 4; ++c)
    Bc[c] = LDW(WTh + c * 8192 + lane * 8);

  // ---------------- phase 0: params + features into T0 (256 rows) ----------
  if (t < 256){
    const float gm = gamma[bi * 256 + t];
    const float bt = beta[bi * 256 + t];
    Pgs[t] = gm;
    C2s[0][t] = fmaf(b0[t], gm, bt);
    C2s[1][t] = fmaf(b1[t], gm, bt);
    C2s[2][t] = fmaf(b2[t], gm, bt);
    C2s[3][t] = fmaf(b3[t], gm, bt);
  }

#pragma unroll
  for (int pass = 0; pass < 2; ++pass){
    const int r = pass * 128 + (t >> 2), q = t & 3;   // 4 threads/row
    const int n = n0 + r;
    const float cy = coords[2 * n], cx = coords[2 * n + 1];

    if (q == 0){
      if (peh){
        const unsigned short* ph = peh + (size_t)n * 48;
#pragma unroll
        for (int u = 0; u < 6; ++u){
          us8 vh = *reinterpret_cast<const us8*>(ph + u * 8);
          *reinterpret_cast<us8*>(&T0[ACOL(r, u * 8)]) = vh;
        }
      } else {
        float e[48];
        e[0] = cy; e[1] = cx;
#pragma unroll
        for (int i = 0; i < 10; ++i){
          float f = PI_F * (float)(1 << i);
          float sy, cyv, sx, cxv;
          sincosf(cy * f, &sy, &cyv);
          sincosf(cx * f, &sx, &cxv);
          e[2 + 4 * i] = sy;
          e[3 + 4 * i] = sx;
          e[4 + 4 * i] = cyv;
          e[5 + 4 * i] = cxv;
        }
#pragma unroll
        for (int j = 42; j < 48; ++j) e[j] = 0.0f;
#pragma unroll
        for (int u = 0; u < 6; ++u){
          us8 vh;
#pragma unroll
          for (int j = 0; j < 8; ++j) vh[j] = f2h(e[8 * u + j]);
          *reinterpret_cast<us8*>(&T0[ACOL(r, u * 8)]) = vh;
        }
      }
    }
    if (q == 1){   // zero pad cols 240..255
      us8 z = {0,0,0,0,0,0,0,0};
      *reinterpret_cast<us8*>(&T0[ACOL(r, 240)]) = z;
      *reinterpret_cast<us8*>(&T0[ACOL(r, 248)]) = z;
    }

    // bilinear sample 16 channels per thread from each pyramid level
#pragma unroll
    for (int L = 0; L < 3; ++L){
      const int HL = 64 >> L;
      const float* g = (L == 0) ? fg : ((L == 1) ? p1 : p2);
      float yy = (cy + 1.0f) * 0.5f * (HL - 1);
      float xx = (cx + 1.0f) * 0.5f * (HL - 1);
      float y0f = floorf(yy), x0f = floorf(xx);
      float wy = yy - y0f, wx = xx - x0f;
      int y0 = (int)y0f, x0 = (int)x0f;
      y0 = min(max(y0, 0), HL - 1); x0 = min(max(x0, 0), HL - 1);
      int y1 = min(y0 + 1, HL - 1), x1 = min(x0 + 1, HL - 1);
      const int c0 = q * 16;
      const float* g00 = g + (((bi * HL + y0) * HL) + x0) * 64 + c0;
      const float* g01 = g + (((bi * HL + y0) * HL) + x1) * 64 + c0;
      const float* g10 = g + (((bi * HL + y1) * HL) + x0) * 64 + c0;
      const float* g11 = g + (((bi * HL + y1) * HL) + x1) * 64 + c0;
      float w00 = (1 - wy) * (1 - wx), w01 = (1 - wy) * wx;
      float w10 = wy * (1 - wx),       w11 = wy * wx;
      float o[16];
#pragma unroll
      for (int u = 0; u < 4; ++u){
        float4 v0 = *reinterpret_cast<const float4*>(g00 + 4 * u);
        float4 v1 = *reinterpret_cast<const float4*>(g01 + 4 * u);
        float4 v2 = *reinterpret_cast<const float4*>(g10 + 4 * u);
        float4 v3 = *reinterpret_cast<const float4*>(g11 + 4 * u);
        o[4*u+0] = w00*v0.x + w01*v1.x + w10*v2.x + w11*v3.x;
        o[4*u+1] = w00*v0.y + w01*v1.y + w10*v2.y + w11*v3.y;
        o[4*u+2] = w00*v0.z + w01*v1.z + w10*v2.z + w11*v3.z;
        o[4*u+3] = w00*v0.w + w01*v1.w + w10*v2.w + w11*v3.w;
      }
      us8 h0, h1;
#pragma unroll
      for (int j = 0; j < 8; ++j){
        h0[j] = f2h(o[j]);
        h1[j] = f2h(o[8 + j]);
      }
      const int colb = 48 + 64 * L + 16 * q;
      *reinterpret_cast<us8*>(&T0[ACOL(r, colb)])     = h0;
      *reinterpret_cast<us8*>(&T0[ACOL(r, colb + 8)]) = h1;
    }
  }
  __syncthreads();   // the ONLY barrier: phase-0 row mapping is cross-wave

  // ---------------- 4 FiLM-gelu MLP layers, barrier-free, 2 passes ---------
  f32x16 acc[4];
  f16x8 st[8];       // pass-A stash (cols 0..127)

#pragma unroll
  for (int l = 0; l < 4; ++l){
    const unsigned short* Wl = WTh + l * 65536;

    // ---- pass A: col groups 0..3, K over full row ----
#pragma unroll
    for (int j = 0; j < 16; ++j){
#pragma unroll
      for (int c = 0; c < 4; ++c) acc[c][j] = 0.0f;
    }
#pragma unroll
    for (int ks = 0; ks < 16; ++ks){
      f16x8 ah = LDW(&T0[ACOL(arow, ks * 16 + lhi * 8)]);
#pragma unroll
      for (int c = 0; c < 4; ++c){
        f16x8 b = Bc[c];
        if (ks < 15) Bc[c] = LDW(Wl + c * 8192 + (ks + 1) * 512 + lane * 8);
        else         Bc[c] = LDW(Wl + (c + 4) * 8192 + lane * 8);  // pass B ks0
        acc[c] = __builtin_amdgcn_mfma_f32_32x32x16_f16(b, ah, acc[c], 0, 0, 0);
      }
    }
    // stash pass-A FiLM+gelu results in registers (NO LDS writes yet)
#pragma unroll
    for (int c = 0; c < 4; ++c){
#pragma unroll
      for (int gp = 0; gp < 2; ++gp){
        const int cb2 = c * 32 + 16 * gp + 4 * lhi;
        const float4 gmA = *reinterpret_cast<const float4*>(&Pgs[cb2]);
        const float4 c2A = *reinterpret_cast<const float4*>(&C2s[l][cb2]);
        const float4 gmB = *reinterpret_cast<const float4*>(&Pgs[cb2 + 8]);
        const float4 c2B = *reinterpret_cast<const float4*>(&C2s[l][cb2 + 8]);
        us8 hv;
        hv[0] = f2h(fast_gelu(fmaf(acc[c][8*gp+0], gmA.x, c2A.x)));
        hv[1] = f2h(fast_gelu(fmaf(acc[c][8*gp+1], gmA.y, c2A.y)));
        hv[2] = f2h(fast_gelu(fmaf(acc[c][8*gp+2], gmA.z, c2A.z)));
        hv[3] = f2h(fast_gelu(fmaf(acc[c][8*gp+3], gmA.w, c2A.w)));
        hv[4] = f2h(fast_gelu(fmaf(acc[c][8*gp+4], gmB.x, c2B.x)));
        hv[5] = f2h(fast_gelu(fmaf(acc[c][8*gp+5], gmB.y, c2B.y)));
        hv[6] = f2h(fast_gelu(fmaf(acc[c][8*gp+6], gmB.z, c2B.z)));
        hv[7] = f2h(fast_gelu(fmaf(acc[c][8*gp+7], gmB.w, c2B.w)));
        st[c * 2 + gp] = __builtin_bit_cast(f16x8, hv);
      }
    }

    // ---- pass B: col groups 4..7, K over the (still intact) row ----
#pragma unroll
    for (int j = 0; j < 16; ++j){
#pragma unroll
      for (int c = 0; c < 4; ++c) acc[c][j] = 0.0f;
    }
#pragma unroll
    for (int ks = 0; ks < 16; ++ks){
      f16x8 ah = LDW(&T0[ACOL(arow, ks * 16 + lhi * 8)]);
#pragma unroll
      for (int c = 0; c < 4; ++c){
        f16x8 b = Bc[c];
        if (ks < 15)
          Bc[c] = LDW(Wl + (c + 4) * 8192 + (ks + 1) * 512 + lane * 8);
        else if (l < 3)
          Bc[c] = LDW(Wl + 65536 + c * 8192 + lane * 8);  // next layer pass A
        acc[c] = __builtin_amdgcn_mfma_f32_32x32x16_f16(b, ah, acc[c], 0, 0, 0);
      }
    }

    // ---- all reads of the row done: write stash (cols 0..127) ----
#pragma unroll
    for (int c = 0; c < 4; ++c){
#pragma unroll
      for (int gp = 0; gp < 2; ++gp){
        us8 v = __builtin_bit_cast(us8, st[c * 2 + gp]);
        us4 lo4, hi4;
        lo4[0]=v[0]; lo4[1]=v[1]; lo4[2]=v[2]; lo4[3]=v[3];
        hi4[0]=v[4]; hi4[1]=v[5]; hi4[2]=v[6]; hi4[3]=v[7];
        const int cb2 = c * 32 + 16 * gp + 4 * lhi;
        *reinterpret_cast<us4*>(&T0[ACOL(arow, cb2)])     = lo4;
        *reinterpret_cast<us4*>(&T0[ACOL(arow, cb2 + 8)]) = hi4;
      }
    }
    // ---- pass-B epilogue: FiLM+gelu, write cols 128..255 ----
#pragma unroll
    for (int c = 0; c < 4; ++c){
#pragma unroll
      for (int gp = 0; gp < 2; ++gp){
        const int cb2 = 128 + c * 32 + 16 * gp + 4 * lhi;
        const float4 gmA = *reinterpret_cast<const float4*>(&Pgs[cb2]);
        const float4 c2A = *reinterpret_cast<const float4*>(&C2s[l][cb2]);
        const float4 gmB = *reinterpret_cast<const float4*>(&Pgs[cb2 + 8]);
        const float4 c2B = *reinterpret_cast<const float4*>(&C2s[l][cb2 + 8]);
        us4 lo4, hi4;
        lo4[0] = f2h(fast_gelu(fmaf(acc[c][8*gp+0], gmA.x, c2A.x)));
        lo4[1] = f2h(fast_gelu(fmaf(acc[c][8*gp+1], gmA.y, c2A.y)));
        lo4[2] = f2h(fast_gelu(fmaf(acc[c][8*gp+2], gmA.z, c2A.z)));
        lo4[3] = f2h(fast_gelu(fmaf(acc[c][8*gp+3], gmA.w, c2A.w)));
        hi4[0] = f2h(fast_gelu(fmaf(acc[c][8*gp+4], gmB.x, c2B.x)));
        hi4[1] = f2h(fast_gelu(fmaf(acc[c][8*gp+5], gmB.y, c2B.y)));
        hi4[2] = f2h(fast_gelu(fmaf(acc[c][8*gp+6], gmB.z, c2B.z)));
        hi4[3] = f2h(fast_gelu(fmaf(acc[c][8*gp+7], gmB.w, c2B.w)));
        *reinterpret_cast<us4*>(&T0[ACOL(arow, cb2)])     = lo4;
        *reinterpret_cast<us4*>(&T0[ACOL(arow, cb2 + 8)]) = hi4;
      }
    }
    // no barrier: next layer reads only this wave's own rows
  }

  // ---------------- head (256 -> 3) + tanh: reads own rows, no barrier -----
#pragma unroll
  for (int s = 0; s < 2; ++s){
    f32x4 ao = (f32x4){0.0f, 0.0f, 0.0f, 0.0f};
#pragma unroll
    for (int ks = 0; ks < 8; ++ks){
      const int kc = ks * 32 + lg * 8;
      f16x8 va = LDW(&T0[ACOL(wv * 32 + s * 16 + l15, kc)]);
      f16x8 vb = LDW(&WoT[(ks * 64 + lane) * 8]);
      ao = __builtin_amdgcn_mfma_f32_16x16x32_f16(va, vb, ao, 0, 0, 0);
    }
    if (l15 < 3){
      const float bo = bout[l15];
#pragma unroll
      for (int rg2 = 0; rg2 < 4; ++rg2){
        const int row = wv * 32 + s * 16 + lg * 4 + rg2;
        out[((size_t)bi * 16384 + n0 + row) * 3 + l15] = fast_tanh(ao[rg2] + bo);
      }
    }
  }
}

// ------------------------------- launch --------------------------------------
extern "C" void kernel_launch(void* const* d_in, const int* in_sizes, int n_in,
                              void* d_out, int out_size, void* d_ws, size_t ws_size,
                              hipStream_t stream){
  (void)in_sizes; (void)n_in; (void)out_size;
  const float* fg     = (const float*)d_in[0];
  const float* cv     = (const float*)d_in[1];
  const float* coords = (const float*)d_in[2];
  const float* Wc     = (const float*)d_in[3];
  const float* bc     = (const float*)d_in[4];
  const float* W0     = (const float*)d_in[5];
  const float* b0     = (const float*)d_in[6];
  const float* W1     = (const float*)d_in[7];
  const float* b1     = (const float*)d_in[8];
  const float* W2     = (const float*)d_in[9];
  const float* b2     = (const float*)d_in[10];
  const float* W3     = (const float*)d_in[11];
  const float* b3     = (const float*)d_in[12];
  const float* Wout   = (const float*)d_in[13];
  const float* bout   = (const float*)d_in[14];

  char* ws = (char*)d_ws;
  float*          p1    = (float*)(ws);                    // 8*32*32*64 f32 = 2 MB
  float*          p2    = (float*)(ws + 2097152);          // 8*16*16*64 f32 = 512 KB
  unsigned short* WTh   = (unsigned short*)(ws + 2621440); // 4*256*256 f16 = 512 KB
  unsigned short* WoT   = (unsigned short*)(ws + 3670016); // 8*64*8 f16
  float*          gam   = (float*)(ws + 3678208);          // 8*256 f32
  float*          bet   = (float*)(ws + 3686400);          // 8*256 f32
  // PE table (optional, 1.5 MB)
  const size_t PEH_OFF = 4194304, PE_END = 5767168;
  bool use_pe = (ws_size >= PE_END);
  unsigned short* PEh = use_pe ? (unsigned short*)(ws + PEH_OFF) : nullptr;
  float* outp = (float*)d_out;

  pyr_kernel<<<dim3(2048), dim3(256), 0, stream>>>(fg, p1, 32, 32, 2.0f);
  pyr_kernel<<<dim3(512),  dim3(256), 0, stream>>>(fg, p2, 16, 16, 4.0f);
  prep_wt  <<<dim3(1024),  dim3(256), 0, stream>>>(W0, W1, W2, W3, WTh);
  prep_misc<<<dim3(32),    dim3(256), 0, stream>>>(cv, Wc, bc, Wout, gam, bet, WoT);
  if (use_pe)
    pe_kernel<<<dim3(768), dim3(256), 0, stream>>>(coords, PEh);
  dec_main <<<dim3(512),   dim3(512), 0, stream>>>(fg, coords, p1, p2, WTh, WoT,
                                                   PEh,
                                                   gam, bet, b0, b1, b2, b3, bout, outp);
}